// Round 1
// baseline (7896.371 us; speedup 1.0000x reference)
//
#include <hip/hip_runtime.h>
#include <math.h>

// Problem constants
#define Bsz 2048
#define T1  9      // T-1
#define Hs  512
#define IN1 16
#define IN2 15

// ---------------------------------------------------------------------------
// Algebraic simplifications exploited (verified against reference):
//  * enc softmax over features is invariant to the (h@Wh + s@Ws) per-row
//    scalar => a1/a2 constant over time; Wh/Ws unused.
//  * dec attention score = Xe . v + const(b) with v = W2 @ W1x => beta and
//    context constant over decoder steps; dec_attn1_b/dec_attn2_b unused.
// ---------------------------------------------------------------------------

struct StepArgs {
  const float* h_in;   // B x HG
  const float* x;      // B x nx (strided)
  const float* Whh;    // 4HG x HG
  const float* Wih;    // 4HG x nx
  const float* bih;    // 4HG
  const float* bhh;    // 4HG
  float* c;            // B x HG (in/out, in-place safe: owned per element)
  float* h_out;        // B x HG
  float* xe;           // optional extra h destination (X_encoded slice)
  int nx;
  int K;               // HG + nx
  int x_stride;        // row stride of x in floats
  int xe_stride;       // row stride of xe in floats
};

#define BM   64
#define BN   64
#define BK   16
#define NTHR 512

// Fused LSTM step: g = [h|x] @ [Whh|Wih]^T + bih + bhh, then gates.
// Block computes BM batch rows x BN hidden cols (x 4 gates).
__global__ __launch_bounds__(NTHR)
void lstm_step_k(StepArgs A0, StepArgs A1, int HG) {
  const StepArgs A = (blockIdx.z == 0) ? A0 : A1;
  __shared__ float As[BM][BK + 1];
  __shared__ float Bs2[4][BN][BK + 1];
  const int tid = threadIdx.x;
  const int tn = tid & 63;         // output col within tile
  const int tm = tid >> 6;         // 0..7
  const int j0 = blockIdx.x * BN;
  const int m0 = blockIdx.y * BM;
  const int K = A.K;
  const int Hh = HG;

  float acc[4][8];
#pragma unroll
  for (int g = 0; g < 4; ++g)
#pragma unroll
    for (int r = 0; r < 8; ++r) acc[g][r] = 0.f;

  for (int k0 = 0; k0 < K; k0 += BK) {
    // stage A tile: BM x BK (composite [h | x])
    for (int i = tid; i < BM * BK; i += NTHR) {
      int k = i & (BK - 1);
      int m = i >> 4;
      int kg = k0 + k;
      float v = 0.f;
      if (kg < Hh)     v = A.h_in[(size_t)(m0 + m) * Hh + kg];
      else if (kg < K) v = A.x[(size_t)(m0 + m) * A.x_stride + (kg - Hh)];
      As[m][k] = v;
    }
    // stage B tiles: 4 gates x BN rows x BK (composite [Whh | Wih])
    for (int i = tid; i < 4 * BN * BK; i += NTHR) {
      int k = i & (BK - 1);
      int rl = i >> 4;
      int g = rl >> 6;
      int rr = rl & 63;
      int n = g * HG + j0 + rr;
      int kg = k0 + k;
      float v = 0.f;
      if (kg < Hh)     v = A.Whh[(size_t)n * Hh + kg];
      else if (kg < K) v = A.Wih[(size_t)n * A.nx + (kg - Hh)];
      Bs2[g][rr][k] = v;
    }
    __syncthreads();
#pragma unroll
    for (int kk = 0; kk < BK; ++kk) {
      float b0 = Bs2[0][tn][kk];
      float b1 = Bs2[1][tn][kk];
      float b2 = Bs2[2][tn][kk];
      float b3 = Bs2[3][tn][kk];
#pragma unroll
      for (int r = 0; r < 8; ++r) {
        float av = As[tm + 8 * r][kk];  // broadcast across wave (tm uniform)
        acc[0][r] = fmaf(av, b0, acc[0][r]);
        acc[1][r] = fmaf(av, b1, acc[1][r]);
        acc[2][r] = fmaf(av, b2, acc[2][r]);
        acc[3][r] = fmaf(av, b3, acc[3][r]);
      }
    }
    __syncthreads();
  }

  const int j = j0 + tn;
  const float bi = A.bih[j]          + A.bhh[j];
  const float bf = A.bih[HG + j]     + A.bhh[HG + j];
  const float bg = A.bih[2 * HG + j] + A.bhh[2 * HG + j];
  const float bo = A.bih[3 * HG + j] + A.bhh[3 * HG + j];
#pragma unroll
  for (int r = 0; r < 8; ++r) {
    const int m = m0 + tm + 8 * r;
    float gi = acc[0][r] + bi;
    float gf = acc[1][r] + bf;
    float gg = acc[2][r] + bg;
    float go = acc[3][r] + bo;
    float i_ = 1.f / (1.f + expf(-gi));
    float f_ = 1.f / (1.f + expf(-gf));
    float g_ = tanhf(gg);
    float o_ = 1.f / (1.f + expf(-go));
    size_t idx = (size_t)m * HG + j;
    float cn = f_ * A.c[idx] + i_ * g_;
    A.c[idx] = cn;
    float hn = o_ * tanhf(cn);
    A.h_out[idx] = hn;
    if (A.xe) A.xe[(size_t)m * A.xe_stride + j] = hn;
  }
}

// Per-batch encoder attention weights (constant over time) and x_tilde precompute.
__global__ void prep_attn_k(const float* __restrict__ X, const float* __restrict__ yp,
                            const float* __restrict__ encW, const float* __restrict__ encb,
                            float* __restrict__ xt1, float* __restrict__ xt2) {
  const int b = blockIdx.x;
  const int tid = threadIdx.x;  // 64 threads
  __shared__ float wf[T1];
  __shared__ float ypb[T1];
  __shared__ float s1[16], s2[IN2];
  __shared__ float e1[16], e2[IN2];
  if (tid < T1) {
    wf[tid] = encW[2 * Hs + tid];
    ypb[tid] = yp[(size_t)b * T1 + tid];
  }
  __syncthreads();
  const float bb = encb[0];
  if (tid < 16) {
    float acc = bb;
    for (int t = 0; t < T1; ++t) {
      float xv = (tid < IN2) ? X[(size_t)b * (T1 * IN2) + t * IN2 + tid] : ypb[t];
      acc += xv * wf[t];
    }
    s1[tid] = acc;
  } else if (tid < 16 + IN2) {
    int k = tid - 16;
    float acc = bb;
    for (int t = 0; t < T1; ++t)
      acc += X[(size_t)b * (T1 * IN2) + t * IN2 + k] * ypb[t] * wf[t];
    s2[k] = acc;
  }
  __syncthreads();
  if (tid < 16) {
    float m = -1e30f;
    for (int k = 0; k < 16; ++k) m = fmaxf(m, s1[k]);
    e1[tid] = expf(s1[tid] - m);
  } else if (tid < 16 + IN2) {
    int k = tid - 16;
    float m = -1e30f;
    for (int kk = 0; kk < IN2; ++kk) m = fmaxf(m, s2[kk]);
    e2[k] = expf(s2[k] - m);
  }
  __syncthreads();
  if (tid < 16) {
    float sum = 0.f;
    for (int k = 0; k < 16; ++k) sum += e1[k];
    float a = e1[tid] / sum;
    for (int t = 0; t < T1; ++t) {
      float xv = (tid < IN2) ? X[(size_t)b * (T1 * IN2) + t * IN2 + tid] : ypb[t];
      xt1[(size_t)b * (T1 * IN1) + t * IN1 + tid] = a * xv;
    }
  } else if (tid < 16 + IN2) {
    int k = tid - 16;
    float sum = 0.f;
    for (int kk = 0; kk < IN2; ++kk) sum += e2[kk];
    float a = e2[k] / sum;
    for (int t = 0; t < T1; ++t)
      xt2[(size_t)b * (T1 * IN2) + t * IN2 + k] =
          a * X[(size_t)b * (T1 * IN2) + t * IN2 + k] * ypb[t];
  }
}

// v[dd] = sum_h dec_attn2_W[0,h] * dec_attn1_W[h, 4H+dd]
__global__ void prep_v_k(const float* __restrict__ A1W, const float* __restrict__ A2W,
                         float* __restrict__ v) {
  const int dd = blockIdx.x * blockDim.x + threadIdx.x;  // 0..1023
  float acc = 0.f;
  for (int h = 0; h < Hs; ++h) acc += A2W[h] * A1W[(size_t)h * (6 * Hs) + 4 * Hs + dd];
  v[dd] = acc;
}

// Decoder attention (constant across steps): score/softmax/context + y_tilde table.
__global__ void dec_ctx_k(const float* __restrict__ Xe, const float* __restrict__ v,
                          const float* __restrict__ yp, const float* __restrict__ fcW,
                          const float* __restrict__ fcb,
                          float* __restrict__ ctx, float* __restrict__ yt) {
  const int b = blockIdx.x;
  const int tid = threadIdx.x;  // 256
  const float* xb = Xe + (size_t)b * (T1 * 2 * Hs);
  float s[T1];
#pragma unroll
  for (int t = 0; t < T1; ++t) s[t] = 0.f;
  for (int dd = tid; dd < 2 * Hs; dd += 256) {
    float vv = v[dd];
#pragma unroll
    for (int t = 0; t < T1; ++t) s[t] += xb[t * 2 * Hs + dd] * vv;
  }
  __shared__ float red[256];
  __shared__ float score[T1];
  for (int t = 0; t < T1; ++t) {
    red[tid] = s[t];
    __syncthreads();
    for (int off = 128; off > 0; off >>= 1) {
      if (tid < off) red[tid] += red[tid + off];
      __syncthreads();
    }
    if (tid == 0) score[t] = red[0];
    __syncthreads();
  }
  float mx = -1e30f;
#pragma unroll
  for (int t = 0; t < T1; ++t) mx = fmaxf(mx, score[t]);
  float e[T1];
  float sum = 0.f;
#pragma unroll
  for (int t = 0; t < T1; ++t) { e[t] = expf(score[t] - mx); sum += e[t]; }
  const float inv = 1.f / sum;
  float fcacc = 0.f;
  for (int dd = tid; dd < 2 * Hs; dd += 256) {
    float c = 0.f;
#pragma unroll
    for (int t = 0; t < T1; ++t) c += e[t] * xb[t * 2 * Hs + dd];
    c *= inv;
    ctx[(size_t)b * 2 * Hs + dd] = c;
    fcacc += c * fcW[dd];
  }
  red[tid] = fcacc;
  __syncthreads();
  for (int off = 128; off > 0; off >>= 1) {
    if (tid < off) red[tid] += red[tid + off];
    __syncthreads();
  }
  const float cf = red[0] + fcb[0];
  if (tid < T1) yt[(size_t)b * T1 + tid] = cf + yp[(size_t)b * T1 + tid] * fcW[2 * Hs];
}

// y_pred[b] = [d, context] . fc_final_W + b
__global__ void final_out_k(const float* __restrict__ dfin, const float* __restrict__ ctx,
                            const float* __restrict__ Wfin, const float* __restrict__ bfin,
                            float* __restrict__ out) {
  const int b = blockIdx.x;
  const int tid = threadIdx.x;  // 256
  float acc = 0.f;
  for (int j = tid; j < 2 * Hs; j += 256) acc += dfin[(size_t)b * 2 * Hs + j] * Wfin[j];
  for (int j = tid; j < 2 * Hs; j += 256) acc += ctx[(size_t)b * 2 * Hs + j] * Wfin[2 * Hs + j];
  __shared__ float red[256];
  red[tid] = acc;
  __syncthreads();
  for (int off = 128; off > 0; off >>= 1) {
    if (tid < off) red[tid] += red[tid + off];
    __syncthreads();
  }
  if (tid == 0) out[b] = red[0] + bfin[0];
}

extern "C" void kernel_launch(void* const* d_in, const int* in_sizes, int n_in,
                              void* d_out, int out_size, void* d_ws, size_t ws_size,
                              hipStream_t stream) {
  const float* X     = (const float*)d_in[0];
  const float* yp    = (const float*)d_in[1];
  const float* encW  = (const float*)d_in[2];
  const float* encb  = (const float*)d_in[3];
  const float* e0Wih = (const float*)d_in[4];
  const float* e0Whh = (const float*)d_in[5];
  const float* e0bih = (const float*)d_in[6];
  const float* e0bhh = (const float*)d_in[7];
  const float* e1Wih = (const float*)d_in[8];
  const float* e1Whh = (const float*)d_in[9];
  const float* e1bih = (const float*)d_in[10];
  const float* e1bhh = (const float*)d_in[11];
  const float* dA1W  = (const float*)d_in[12];
  const float* dA2W  = (const float*)d_in[14];
  const float* dWih  = (const float*)d_in[16];
  const float* dWhh  = (const float*)d_in[17];
  const float* dbih  = (const float*)d_in[18];
  const float* dbhh  = (const float*)d_in[19];
  const float* fcW   = (const float*)d_in[20];
  const float* fcb   = (const float*)d_in[21];
  const float* WfinW = (const float*)d_in[22];
  const float* Wfinb = (const float*)d_in[23];
  float* out = (float*)d_out;

  float* ws = (float*)d_ws;
  size_t off = 0;
  auto alloc = [&](size_t n) {
    float* p = ws + off;
    off += (n + 63) & ~(size_t)63;
    return p;
  };
  // zero-init region (contiguous, memset once per call)
  float* h1_0 = alloc((size_t)Bsz * Hs);
  float* c1   = alloc((size_t)Bsz * Hs);
  float* h2_0 = alloc((size_t)Bsz * Hs);
  float* c2   = alloc((size_t)Bsz * Hs);
  float* d_0  = alloc((size_t)Bsz * 2 * Hs);
  float* cdec = alloc((size_t)Bsz * 2 * Hs);
  size_t zero_floats = off;
  float* h1_1 = alloc((size_t)Bsz * Hs);
  float* h2_1 = alloc((size_t)Bsz * Hs);
  float* d_1  = alloc((size_t)Bsz * 2 * Hs);
  float* xt1  = alloc((size_t)Bsz * T1 * IN1);
  float* xt2  = alloc((size_t)Bsz * T1 * IN2);
  float* Xe   = alloc((size_t)Bsz * T1 * 2 * Hs);
  float* vv   = alloc(2 * Hs);
  float* yt   = alloc((size_t)Bsz * T1);
  float* ctx  = alloc((size_t)Bsz * 2 * Hs);
  (void)ws_size; (void)in_sizes; (void)n_in; (void)out_size;

  hipMemsetAsync(d_ws, 0, zero_floats * sizeof(float), stream);
  prep_attn_k<<<Bsz, 64, 0, stream>>>(X, yp, encW, encb, xt1, xt2);
  prep_v_k<<<(2 * Hs) / 256, 256, 0, stream>>>(dA1W, dA2W, vv);

  float* h1c = h1_0; float* h1n = h1_1;
  float* h2c = h2_0; float* h2n = h2_1;
  for (int t = 0; t < T1; ++t) {
    StepArgs a0{h1c, xt1 + (size_t)t * IN1, e0Whh, e0Wih, e0bih, e0bhh,
                c1, h1n, Xe + (size_t)t * 2 * Hs, IN1, Hs + IN1, T1 * IN1, T1 * 2 * Hs};
    StepArgs a1{h2c, xt2 + (size_t)t * IN2, e1Whh, e1Wih, e1bih, e1bhh,
                c2, h2n, Xe + (size_t)t * 2 * Hs + Hs, IN2, Hs + IN2, T1 * IN2, T1 * 2 * Hs};
    dim3 grid(Hs / BN, Bsz / BM, 2);
    lstm_step_k<<<grid, NTHR, 0, stream>>>(a0, a1, Hs);
    float* tmp = h1c; h1c = h1n; h1n = tmp;
    tmp = h2c; h2c = h2n; h2n = tmp;
  }

  dec_ctx_k<<<Bsz, 256, 0, stream>>>(Xe, vv, yp, fcW, fcb, ctx, yt);

  float* dc = d_0; float* dn = d_1;
  for (int t = 0; t < T1; ++t) {
    StepArgs a0{dc, yt + t, dWhh, dWih, dbih, dbhh,
                cdec, dn, nullptr, 1, 2 * Hs + 1, T1, 0};
    dim3 grid((2 * Hs) / BN, Bsz / BM, 1);
    lstm_step_k<<<grid, NTHR, 0, stream>>>(a0, a0, 2 * Hs);
    float* tmp = dc; dc = dn; dn = tmp;
  }

  final_out_k<<<Bsz, 256, 0, stream>>>(dc, ctx, WfinW, Wfinb, out);
}

// Round 2
// 990.060 us; speedup vs baseline: 7.9756x; 7.9756x over previous
//
#include <hip/hip_runtime.h>
#include <hip/hip_bf16.h>
#include <math.h>

// Problem constants
#define Bsz 2048
#define T1  9      // T-1
#define Hs  512
#define IN2 15

typedef __bf16 bf16x8 __attribute__((ext_vector_type(8)));
typedef float  f32x4  __attribute__((ext_vector_type(4)));
typedef __hip_bfloat16 bf16;

// ---------------------------------------------------------------------------
// Algebraic simplifications (verified, round-1 passed with absmax 0):
//  * enc softmax over features invariant to (h@Wh+s@Ws) scalar => a1/a2
//    constant over time; Wh/Ws dead.
//  * dec attention: score = Xe.v + const(b), v = W2@W1x => beta/context
//    constant across decoder steps.
// This round: LSTM GEMMs via MFMA bf16x3 (hi/lo split, fp32 accumulate):
//    A.W ~= Ahi.Whi + Ahi.Wlo + Alo.Whi   (error ~2^-16 relative)
// Weight layout n' = (j/16)*64 + g*16 + (j%16): every 64-wide wave tile
// holds all 4 gates for 16 j's -> in-register gate epilogue.
// ---------------------------------------------------------------------------

#define BMT 128   // rows (batch) per block
#define BNP 128   // n' cols per block
#define LDK 40    // padded LDS row length in bf16 (32 data + 8 pad -> 80B)

struct GA {
  const bf16* Ahi;   // B x HG   activations hi
  const bf16* Alo;   // B x HG   activations lo
  const bf16* Axhi;  // B x 16   x-part for this t (or null)
  const bf16* Axlo;
  const bf16* Whi;   // 4HG x Kpad, n'-ordered
  const bf16* Wlo;
  const float* bsum; // 4HG, n'-ordered (bih+bhh)
  const float* wihp; // 4HG, n'-ordered rank-1 weights (dec) or null
  const float* ytp;  // rank-1 activations y_tilde column (dec) or null
  float* c;          // B x HG cell state (in/out)
  bf16* Hhi;         // B x HG h out (hi)
  bf16* Hlo;         // B x HG h out (lo)
  float* hf;         // optional fp32 h out (Xe slice / final d) or null
  int hf_stride;
  int ytstride;
};

__global__ __launch_bounds__(256, 2)
void lstm_mfma_k(GA a0, GA a1, int HG, int Kpad) {
  __shared__ __align__(16) unsigned short As[2][BMT * LDK];
  __shared__ __align__(16) unsigned short Bs[2][BMT * LDK];
  const int tid = threadIdx.x;

  // bijective XCD swizzle (nwg % 8 == 0 for all our launches), mb-fastest
  const int gx = gridDim.x, gy = gridDim.y;
  const int nwg = gx * gy * gridDim.z;
  const int orig = blockIdx.x + gx * (blockIdx.y + gy * blockIdx.z);
  const int q = nwg >> 3;
  const int swz = (orig & 7) * q + (orig >> 3);
  const GA A = (swz >= gx * gy) ? a1 : a0;
  const int rem = swz % (gx * gy);
  const int nb = rem / gy;
  const int mb = rem % gy;
  const int m0 = mb * BMT, n0 = nb * BNP;
  const int KT = Kpad >> 5;

  uint4 sv[8];
  auto stage_load = [&](int kt) {
    const int k0 = kt * 32;
#pragma unroll 8
    for (int ci = 0; ci < 8; ++ci) {
      const int L = ci * 256 + tid;
      const int arr = L >> 9;          // 0:Ahi 1:Alo 2:Whi 3:Wlo
      const int wdx = L & 511;
      const int row = wdx >> 2;
      const int kc = wdx & 3;
      const int ke = k0 + kc * 8;
      uint4 v; v.x = v.y = v.z = v.w = 0u;
      if (arr < 2) {
        if (ke < HG) {
          const bf16* base = arr ? A.Alo : A.Ahi;
          v = *reinterpret_cast<const uint4*>(base + (size_t)(m0 + row) * HG + ke);
        } else if (A.Axhi && ke < HG + 16) {
          const bf16* xb = arr ? A.Axlo : A.Axhi;
          v = *reinterpret_cast<const uint4*>(xb + (size_t)(m0 + row) * 16 + (ke - HG));
        }
      } else {
        const bf16* base = (arr == 3) ? A.Wlo : A.Whi;
        v = *reinterpret_cast<const uint4*>(base + (size_t)(n0 + row) * Kpad + ke);
      }
      sv[ci] = v;
    }
  };

  const int lane = tid & 63;
  const int wv = tid >> 6;
  const int wr = wv >> 1, wc = wv & 1;  // wave grid 2x2, each 64x64
  const int l15 = lane & 15;
  const int lk = (lane >> 4) * 8;

  int aoff[4], boff[4];
#pragma unroll
  for (int mi = 0; mi < 4; ++mi) aoff[mi] = (wr * 64 + mi * 16 + l15) * LDK + lk;
#pragma unroll
  for (int ni = 0; ni < 4; ++ni) boff[ni] = (wc * 64 + ni * 16 + l15) * LDK + lk;

  f32x4 acc[4][4] = {};

  stage_load(0);
  for (int kt = 0; kt < KT; ++kt) {
    __syncthreads();  // previous tile's reads done
#pragma unroll 8
    for (int ci = 0; ci < 8; ++ci) {
      const int L = ci * 256 + tid;
      const int arr = L >> 9;
      const int wdx = L & 511;
      const int row = wdx >> 2;
      const int kc = wdx & 3;
      unsigned short* dst = (arr < 2 ? &As[arr][0] : &Bs[arr - 2][0]) + row * LDK + kc * 8;
      *reinterpret_cast<uint4*>(dst) = sv[ci];
    }
    __syncthreads();  // tile ready

    bf16x8 ah[4], al[4];
#pragma unroll
    for (int mi = 0; mi < 4; ++mi) {
      ah[mi] = __builtin_bit_cast(bf16x8, *reinterpret_cast<const uint4*>(&As[0][aoff[mi]]));
      al[mi] = __builtin_bit_cast(bf16x8, *reinterpret_cast<const uint4*>(&As[1][aoff[mi]]));
    }
    if (kt + 1 < KT) stage_load(kt + 1);  // overlap next-tile global loads with MFMA
#pragma unroll
    for (int ni = 0; ni < 4; ++ni) {
      bf16x8 bh = __builtin_bit_cast(bf16x8, *reinterpret_cast<const uint4*>(&Bs[0][boff[ni]]));
      bf16x8 bl = __builtin_bit_cast(bf16x8, *reinterpret_cast<const uint4*>(&Bs[1][boff[ni]]));
#pragma unroll
      for (int mi = 0; mi < 4; ++mi) {
        acc[mi][ni] = __builtin_amdgcn_mfma_f32_16x16x32_bf16(ah[mi], bh, acc[mi][ni], 0, 0, 0);
        acc[mi][ni] = __builtin_amdgcn_mfma_f32_16x16x32_bf16(ah[mi], bl, acc[mi][ni], 0, 0, 0);
        acc[mi][ni] = __builtin_amdgcn_mfma_f32_16x16x32_bf16(al[mi], bh, acc[mi][ni], 0, 0, 0);
      }
    }
  }

  // Epilogue: ni == gate index g; j = nb*32 + wc*16 + (lane&15)
  const int j = nb * 32 + wc * 16 + l15;
  const int npb = nb * 128 + wc * 64 + l15;
  const float bs0 = A.bsum[npb], bs1 = A.bsum[npb + 16];
  const float bs2 = A.bsum[npb + 32], bs3 = A.bsum[npb + 48];
  float w0 = 0.f, w1 = 0.f, w2 = 0.f, w3 = 0.f;
  if (A.wihp) {
    w0 = A.wihp[npb]; w1 = A.wihp[npb + 16];
    w2 = A.wihp[npb + 32]; w3 = A.wihp[npb + 48];
  }
#pragma unroll
  for (int mi = 0; mi < 4; ++mi) {
#pragma unroll
    for (int r = 0; r < 4; ++r) {
      const int rowl = wr * 64 + mi * 16 + (lane >> 4) * 4 + r;
      const size_t rowg = m0 + rowl;
      float gi = acc[mi][0][r] + bs0;
      float gf = acc[mi][1][r] + bs1;
      float gg = acc[mi][2][r] + bs2;
      float go = acc[mi][3][r] + bs3;
      if (A.ytp) {
        const float yv = A.ytp[rowg * A.ytstride];
        gi += yv * w0; gf += yv * w1; gg += yv * w2; go += yv * w3;
      }
      const float i_ = 1.f / (1.f + __expf(-gi));
      const float f_ = 1.f / (1.f + __expf(-gf));
      const float tg = __expf(2.f * gg);
      const float g_ = (tg - 1.f) / (tg + 1.f);
      const float o_ = 1.f / (1.f + __expf(-go));
      const size_t idx = rowg * HG + j;
      const float cn = f_ * A.c[idx] + i_ * g_;
      A.c[idx] = cn;
      const float tc = __expf(2.f * cn);
      const float hn = o_ * (tc - 1.f) / (tc + 1.f);
      const bf16 hh = __float2bfloat16(hn);
      A.Hhi[idx] = hh;
      A.Hlo[idx] = __float2bfloat16(hn - __bfloat162float(hh));
      if (A.hf) A.hf[rowg * A.hf_stride + j] = hn;
    }
  }
}

// Build composite weights in n'-interleaved order, split hi/lo; bsum; wihp.
__global__ void build_w_k(const float* __restrict__ Whh, const float* __restrict__ Wih,
                          const float* __restrict__ bih, const float* __restrict__ bhh,
                          bf16* __restrict__ Whi, bf16* __restrict__ Wlo,
                          float* __restrict__ bsum, float* __restrict__ wihp,
                          int HG, int nx, int Kpad) {
  const size_t total = (size_t)4 * HG * Kpad;
  for (size_t idx = (size_t)blockIdx.x * 256 + threadIdx.x; idx < total;
       idx += (size_t)gridDim.x * 256) {
    const int np = (int)(idx / Kpad);
    const int k = (int)(idx % Kpad);
    const int g = (np >> 4) & 3;
    const int jj = ((np >> 6) << 4) + (np & 15);
    const int norig = g * HG + jj;
    float v = 0.f;
    if (k < HG) v = Whh[(size_t)norig * HG + k];
    else if (k - HG < nx) v = Wih[(size_t)norig * nx + (k - HG)];
    const bf16 h = __float2bfloat16(v);
    Whi[idx] = h;
    Wlo[idx] = __float2bfloat16(v - __bfloat162float(h));
    if (k == 0) {
      bsum[np] = bih[norig] + bhh[norig];
      if (wihp) wihp[np] = Wih[norig];  // dec: Wih is (8H,1)
    }
  }
}

// Per-batch encoder attention weights (time-invariant) -> x_tilde hi/lo tables.
__global__ void prep_attn_k(const float* __restrict__ X, const float* __restrict__ yp,
                            const float* __restrict__ encW, const float* __restrict__ encb,
                            bf16* __restrict__ x1h, bf16* __restrict__ x1l,
                            bf16* __restrict__ x2h, bf16* __restrict__ x2l) {
  const int b = blockIdx.x;
  const int tid = threadIdx.x;  // 64
  __shared__ float wf[T1], ypb[T1];
  __shared__ float s1[16], s2[IN2], e1[16], e2[IN2];
  if (tid < T1) {
    wf[tid] = encW[2 * Hs + tid];
    ypb[tid] = yp[(size_t)b * T1 + tid];
  }
  __syncthreads();
  const float bb = encb[0];
  if (tid < 16) {
    float acc = bb;
    for (int t = 0; t < T1; ++t) {
      float xv = (tid < IN2) ? X[(size_t)b * (T1 * IN2) + t * IN2 + tid] : ypb[t];
      acc += xv * wf[t];
    }
    s1[tid] = acc;
  } else if (tid < 16 + IN2) {
    const int k = tid - 16;
    float acc = bb;
    for (int t = 0; t < T1; ++t)
      acc += X[(size_t)b * (T1 * IN2) + t * IN2 + k] * ypb[t] * wf[t];
    s2[k] = acc;
  }
  __syncthreads();
  if (tid < 16) {
    float m = -1e30f;
    for (int k = 0; k < 16; ++k) m = fmaxf(m, s1[k]);
    e1[tid] = expf(s1[tid] - m);
  } else if (tid < 16 + IN2) {
    const int k = tid - 16;
    float m = -1e30f;
    for (int kk = 0; kk < IN2; ++kk) m = fmaxf(m, s2[kk]);
    e2[k] = expf(s2[k] - m);
  }
  __syncthreads();
  if (tid < 16) {
    float sum = 0.f;
    for (int k = 0; k < 16; ++k) sum += e1[k];
    const float a = e1[tid] / sum;
    for (int t = 0; t < T1; ++t) {
      float xv = (tid < IN2) ? X[(size_t)b * (T1 * IN2) + t * IN2 + tid] : ypb[t];
      const float v = a * xv;
      const size_t o = ((size_t)t * Bsz + b) * 16 + tid;
      const bf16 h = __float2bfloat16(v);
      x1h[o] = h; x1l[o] = __float2bfloat16(v - __bfloat162float(h));
    }
  } else if (tid < 16 + IN2) {
    const int k = tid - 16;
    float sum = 0.f;
    for (int kk = 0; kk < IN2; ++kk) sum += e2[kk];
    const float a = e2[k] / sum;
    for (int t = 0; t < T1; ++t) {
      const float v = a * X[(size_t)b * (T1 * IN2) + t * IN2 + k] * ypb[t];
      const size_t o = ((size_t)t * Bsz + b) * 16 + k;
      const bf16 h = __float2bfloat16(v);
      x2h[o] = h; x2l[o] = __float2bfloat16(v - __bfloat162float(h));
    }
  } else if (tid == 31) {
    const bf16 z = __float2bfloat16(0.f);
    for (int t = 0; t < T1; ++t) {
      const size_t o = ((size_t)t * Bsz + b) * 16 + 15;
      x2h[o] = z; x2l[o] = z;
    }
  }
}

// v[dd] = sum_h dec_attn2_W[0,h] * dec_attn1_W[h, 4H+dd]
__global__ void prep_v_k(const float* __restrict__ A1W, const float* __restrict__ A2W,
                         float* __restrict__ v) {
  const int dd = blockIdx.x * blockDim.x + threadIdx.x;
  float acc = 0.f;
  for (int h = 0; h < Hs; ++h) acc += A2W[h] * A1W[(size_t)h * (6 * Hs) + 4 * Hs + dd];
  v[dd] = acc;
}

// Decoder attention (step-invariant): softmax over t, context, y_tilde table.
__global__ void dec_ctx_k(const float* __restrict__ Xe, const float* __restrict__ v,
                          const float* __restrict__ yp, const float* __restrict__ fcW,
                          const float* __restrict__ fcb,
                          float* __restrict__ ctx, float* __restrict__ yt) {
  const int b = blockIdx.x;
  const int tid = threadIdx.x;  // 256
  const float* xb = Xe + (size_t)b * (T1 * 2 * Hs);
  float s[T1];
#pragma unroll
  for (int t = 0; t < T1; ++t) s[t] = 0.f;
  for (int dd = tid; dd < 2 * Hs; dd += 256) {
    const float vv = v[dd];
#pragma unroll
    for (int t = 0; t < T1; ++t) s[t] += xb[t * 2 * Hs + dd] * vv;
  }
  __shared__ float red[256];
  __shared__ float score[T1];
  for (int t = 0; t < T1; ++t) {
    red[tid] = s[t];
    __syncthreads();
    for (int off = 128; off > 0; off >>= 1) {
      if (tid < off) red[tid] += red[tid + off];
      __syncthreads();
    }
    if (tid == 0) score[t] = red[0];
    __syncthreads();
  }
  float mx = -1e30f;
#pragma unroll
  for (int t = 0; t < T1; ++t) mx = fmaxf(mx, score[t]);
  float e[T1];
  float sum = 0.f;
#pragma unroll
  for (int t = 0; t < T1; ++t) { e[t] = expf(score[t] - mx); sum += e[t]; }
  const float inv = 1.f / sum;
  float fcacc = 0.f;
  for (int dd = tid; dd < 2 * Hs; dd += 256) {
    float c = 0.f;
#pragma unroll
    for (int t = 0; t < T1; ++t) c += e[t] * xb[t * 2 * Hs + dd];
    c *= inv;
    ctx[(size_t)b * 2 * Hs + dd] = c;
    fcacc += c * fcW[dd];
  }
  red[tid] = fcacc;
  __syncthreads();
  for (int off = 128; off > 0; off >>= 1) {
    if (tid < off) red[tid] += red[tid + off];
    __syncthreads();
  }
  const float cf = red[0] + fcb[0];
  if (tid < T1) yt[(size_t)b * T1 + tid] = cf + yp[(size_t)b * T1 + tid] * fcW[2 * Hs];
}

__global__ void final_out_k(const float* __restrict__ dfin, const float* __restrict__ ctx,
                            const float* __restrict__ Wfin, const float* __restrict__ bfin,
                            float* __restrict__ out) {
  const int b = blockIdx.x;
  const int tid = threadIdx.x;  // 256
  float acc = 0.f;
  for (int jj = tid; jj < 2 * Hs; jj += 256) acc += dfin[(size_t)b * 2 * Hs + jj] * Wfin[jj];
  for (int jj = tid; jj < 2 * Hs; jj += 256) acc += ctx[(size_t)b * 2 * Hs + jj] * Wfin[2 * Hs + jj];
  __shared__ float red[256];
  red[tid] = acc;
  __syncthreads();
  for (int off = 128; off > 0; off >>= 1) {
    if (tid < off) red[tid] += red[tid + off];
    __syncthreads();
  }
  if (tid == 0) out[b] = red[0] + bfin[0];
}

extern "C" void kernel_launch(void* const* d_in, const int* in_sizes, int n_in,
                              void* d_out, int out_size, void* d_ws, size_t ws_size,
                              hipStream_t stream) {
  const float* X     = (const float*)d_in[0];
  const float* yp    = (const float*)d_in[1];
  const float* encW  = (const float*)d_in[2];
  const float* encb  = (const float*)d_in[3];
  const float* e0Wih = (const float*)d_in[4];
  const float* e0Whh = (const float*)d_in[5];
  const float* e0bih = (const float*)d_in[6];
  const float* e0bhh = (const float*)d_in[7];
  const float* e1Wih = (const float*)d_in[8];
  const float* e1Whh = (const float*)d_in[9];
  const float* e1bih = (const float*)d_in[10];
  const float* e1bhh = (const float*)d_in[11];
  const float* dA1W  = (const float*)d_in[12];
  const float* dA2W  = (const float*)d_in[14];
  const float* dWih  = (const float*)d_in[16];
  const float* dWhh  = (const float*)d_in[17];
  const float* dbih  = (const float*)d_in[18];
  const float* dbhh  = (const float*)d_in[19];
  const float* fcW   = (const float*)d_in[20];
  const float* fcb   = (const float*)d_in[21];
  const float* WfinW = (const float*)d_in[22];
  const float* Wfinb = (const float*)d_in[23];
  float* out = (float*)d_out;
  (void)in_sizes; (void)n_in; (void)out_size; (void)ws_size;

  char* wsb = (char*)d_ws;
  size_t off = 0;
  auto alloc = [&](size_t bytes) -> void* {
    void* p = wsb + off;
    off = (off + bytes + 255) & ~(size_t)255;
    return p;
  };
  const size_t BH  = (size_t)Bsz * Hs;       // 1M
  const size_t BH2 = (size_t)Bsz * 2 * Hs;   // 2M
  // ---- zero-init region (one memset per call) ----
  float* c1   = (float*)alloc(BH * 4);
  float* c2   = (float*)alloc(BH * 4);
  float* cdec = (float*)alloc(BH2 * 4);
  bf16* h1hi0 = (bf16*)alloc(BH * 2);
  bf16* h1lo0 = (bf16*)alloc(BH * 2);
  bf16* h2hi0 = (bf16*)alloc(BH * 2);
  bf16* h2lo0 = (bf16*)alloc(BH * 2);
  bf16* dhi0  = (bf16*)alloc(BH2 * 2);
  bf16* dlo0  = (bf16*)alloc(BH2 * 2);
  const size_t zero_bytes = off;
  // ---- rest ----
  bf16* h1hi1 = (bf16*)alloc(BH * 2);
  bf16* h1lo1 = (bf16*)alloc(BH * 2);
  bf16* h2hi1 = (bf16*)alloc(BH * 2);
  bf16* h2lo1 = (bf16*)alloc(BH * 2);
  bf16* dhi1  = (bf16*)alloc(BH2 * 2);
  bf16* dlo1  = (bf16*)alloc(BH2 * 2);
  bf16* W0hi  = (bf16*)alloc((size_t)2048 * 544 * 2);
  bf16* W0lo  = (bf16*)alloc((size_t)2048 * 544 * 2);
  bf16* W1hi  = (bf16*)alloc((size_t)2048 * 544 * 2);
  bf16* W1lo  = (bf16*)alloc((size_t)2048 * 544 * 2);
  bf16* Wdhi  = (bf16*)alloc((size_t)4096 * 1024 * 2);
  bf16* Wdlo  = (bf16*)alloc((size_t)4096 * 1024 * 2);
  float* bs0  = (float*)alloc(2048 * 4);
  float* bs1  = (float*)alloc(2048 * 4);
  float* bsd  = (float*)alloc(4096 * 4);
  float* wihp = (float*)alloc(4096 * 4);
  bf16* x1h   = (bf16*)alloc((size_t)T1 * Bsz * 16 * 2);
  bf16* x1l   = (bf16*)alloc((size_t)T1 * Bsz * 16 * 2);
  bf16* x2h   = (bf16*)alloc((size_t)T1 * Bsz * 16 * 2);
  bf16* x2l   = (bf16*)alloc((size_t)T1 * Bsz * 16 * 2);
  float* Xe   = (float*)alloc((size_t)Bsz * T1 * 2 * Hs * 4);
  float* dfp  = (float*)alloc(BH2 * 4);
  float* ctx  = (float*)alloc(BH2 * 4);
  float* vv   = (float*)alloc(2 * Hs * 4);
  float* yt   = (float*)alloc((size_t)Bsz * T1 * 4);

  hipMemsetAsync(d_ws, 0, zero_bytes, stream);

  build_w_k<<<4096, 256, 0, stream>>>(e0Whh, e0Wih, e0bih, e0bhh, W0hi, W0lo, bs0, nullptr, Hs, 16, 544);
  build_w_k<<<4096, 256, 0, stream>>>(e1Whh, e1Wih, e1bih, e1bhh, W1hi, W1lo, bs1, nullptr, Hs, 15, 544);
  build_w_k<<<4096, 256, 0, stream>>>(dWhh, dWih, dbih, dbhh, Wdhi, Wdlo, bsd, wihp, 2 * Hs, 0, 1024);
  prep_attn_k<<<Bsz, 64, 0, stream>>>(X, yp, encW, encb, x1h, x1l, x2h, x2l);
  prep_v_k<<<(2 * Hs) / 256, 256, 0, stream>>>(dA1W, dA2W, vv);

  // ---- encoder: 9 steps, both branches per launch ----
  bf16 *h1hc = h1hi0, *h1lc = h1lo0, *h1hn = h1hi1, *h1ln = h1lo1;
  bf16 *h2hc = h2hi0, *h2lc = h2lo0, *h2hn = h2hi1, *h2ln = h2lo1;
  for (int t = 0; t < T1; ++t) {
    GA a0{h1hc, h1lc, x1h + (size_t)t * Bsz * 16, x1l + (size_t)t * Bsz * 16,
          W0hi, W0lo, bs0, nullptr, nullptr,
          c1, h1hn, h1ln, Xe + (size_t)t * 2 * Hs, T1 * 2 * Hs, 0};
    GA a1{h2hc, h2lc, x2h + (size_t)t * Bsz * 16, x2l + (size_t)t * Bsz * 16,
          W1hi, W1lo, bs1, nullptr, nullptr,
          c2, h2hn, h2ln, Xe + (size_t)t * 2 * Hs + Hs, T1 * 2 * Hs, 0};
    dim3 grid((4 * Hs) / BNP, Bsz / BMT, 2);
    lstm_mfma_k<<<grid, 256, 0, stream>>>(a0, a1, Hs, 544);
    bf16* tp;
    tp = h1hc; h1hc = h1hn; h1hn = tp;  tp = h1lc; h1lc = h1ln; h1ln = tp;
    tp = h2hc; h2hc = h2hn; h2hn = tp;  tp = h2lc; h2lc = h2ln; h2ln = tp;
  }

  dec_ctx_k<<<Bsz, 256, 0, stream>>>(Xe, vv, yp, fcW, fcb, ctx, yt);

  // ---- decoder: 9 steps ----
  bf16 *dhc = dhi0, *dlc = dlo0, *dhn = dhi1, *dln = dlo1;
  for (int t = 0; t < T1; ++t) {
    GA a0{dhc, dlc, nullptr, nullptr,
          Wdhi, Wdlo, bsd, wihp, yt + t,
          cdec, dhn, dln, (t == T1 - 1) ? dfp : nullptr, 2 * Hs, T1};
    dim3 grid((8 * Hs) / BNP, Bsz / BMT, 1);
    lstm_mfma_k<<<grid, 256, 0, stream>>>(a0, a0, 2 * Hs, 1024);
    bf16* tp;
    tp = dhc; dhc = dhn; dhn = tp;  tp = dlc; dlc = dln; dln = tp;
  }

  final_out_k<<<Bsz, 256, 0, stream>>>(dfp, ctx, WfinW, Wfinb, out);
}